// Round 1
// baseline (801.551 us; speedup 1.0000x reference)
//
#include <hip/hip_runtime.h>
#include <stdint.h>

// ============================================================================
// WindowCrossAttention on MI355X (gfx950)
//   B=4096 windows, N=64 tokens, C=128, H=4 heads, HD=32, NW=1024 mask groups.
//   One block (512 thr = 8 waves) per window; fully fused:
//     QKV gemm -> cross attention (softmax in-reg) -> proj + residual + LN.
//   bf16 MFMA 16x16x32 (verified layouts: A m=lane&15,k=quad*8+j; C col=lane&15,
//   row=quad*4+reg). fp32 accumulation, residual/LN in fp32.
// ============================================================================

typedef __attribute__((ext_vector_type(8))) short short8;  // 8 bf16, 4 VGPRs
typedef __attribute__((ext_vector_type(4))) float f32x4;   // MFMA C/D frag

#define MFMA(a, b, c) __builtin_amdgcn_mfma_f32_16x16x32_bf16((a), (b), (c), 0, 0, 0)

static __device__ __forceinline__ unsigned short f2bf(float f) {
  union { float f; uint32_t u; } v; v.f = f;
  uint32_t u = v.u + (0x7fffu + ((v.u >> 16) & 1u));  // RNE, no NaN in data
  return (unsigned short)(u >> 16);
}

// ---------------------------------------------------------------------------
// Prep: pack weights to bf16 fragment-major (B-operand of 16x16x32 tiles),
// gather bias tables tbl[rpi] -> (H,64,64) fp32.
// Fragment-major: tile index (nt*KT + kt), then lane (64), then j (8 contig).
// ---------------------------------------------------------------------------
__global__ __launch_bounds__(256) void prep_kernel(
    const float* __restrict__ wqkv1, const float* __restrict__ wqkv2,
    const float* __restrict__ wproj1, const float* __restrict__ wproj2,
    const float* __restrict__ tbl1, const float* __restrict__ tbl2,
    const int* __restrict__ rpi,
    unsigned short* __restrict__ wq1p, unsigned short* __restrict__ wq2p,
    unsigned short* __restrict__ wp1p, unsigned short* __restrict__ wp2p,
    float* __restrict__ bias1, float* __restrict__ bias2) {
  int tid = blockIdx.x * 256 + threadIdx.x;
  if (tid < 12288) {  // wqkv1 / wqkv2: K=128 (kt 0..3), N=384 (nt 0..23): 96 tiles * 64 lanes
    const float* W = (tid < 6144) ? wqkv1 : wqkv2;
    unsigned short* P = (tid < 6144) ? wq1p : wq2p;
    int local = (tid < 6144) ? tid : tid - 6144;
    int tile = local >> 6, lane = local & 63;
    int nt = tile >> 2, kt = tile & 3;
    int n = nt * 16 + (lane & 15);
    int kb = kt * 32 + (lane >> 4) * 8;
    unsigned short* dst = P + (size_t)(tile * 64 + lane) * 8;
#pragma unroll
    for (int j = 0; j < 8; ++j) dst[j] = f2bf(W[(kb + j) * 384 + n]);
  } else if (tid < 16384) {  // wproj1 / wproj2: 32 tiles * 64 lanes each
    int local = tid - 12288;
    const float* W = (local < 2048) ? wproj1 : wproj2;
    unsigned short* P = (local < 2048) ? wp1p : wp2p;
    local &= 2047;
    int tile = local >> 6, lane = local & 63;
    int nt = tile >> 2, kt = tile & 3;
    int n = nt * 16 + (lane & 15);
    int kb = kt * 32 + (lane >> 4) * 8;
    unsigned short* dst = P + (size_t)(tile * 64 + lane) * 8;
#pragma unroll
    for (int j = 0; j < 8; ++j) dst[j] = f2bf(W[(kb + j) * 128 + n]);
  } else if (tid < 49152) {  // bias gather: bias[h][i][j] = tbl[rpi[i][j]][h]
    int local = tid - 16384;
    const float* T = (local < 16384) ? tbl1 : tbl2;
    float* D = (local < 16384) ? bias1 : bias2;
    local &= 16383;
    int h = local >> 12, ij = local & 4095;
    D[local] = T[rpi[ij] * 4 + h];
  }
}

// ---------------------------------------------------------------------------
// Main fused kernel. LDS plan (155648 B total):
//   sQ [2][4][64][40] bf16 : q per side/head, row-major (token, hd) pad->40
//   sK [2][4][64][40] bf16 : k per side/head
//   sVT[2][4][32][72] bf16 : v TRANSPOSED (hd, token) so PV B-frags contiguous
//   sP [4][64][72]    bf16 : softmax probs per head (C-layout -> A-layout xform)
//   sO (attention out, [64][136]) aliases sQ[side] (q dead after its PV).
// ---------------------------------------------------------------------------
__global__ __launch_bounds__(512, 2) void wca_kernel(
    const float* __restrict__ x, const float* __restrict__ y,
    const float* __restrict__ mask,
    const float* __restrict__ bqkv1, const float* __restrict__ bqkv2,
    const float* __restrict__ bproj1, const float* __restrict__ bproj2,
    const float* __restrict__ g1, const float* __restrict__ be1,
    const float* __restrict__ g2, const float* __restrict__ be2,
    const unsigned short* __restrict__ wq1p, const unsigned short* __restrict__ wq2p,
    const unsigned short* __restrict__ wp1p, const unsigned short* __restrict__ wp2p,
    const float* __restrict__ biasT1, const float* __restrict__ biasT2,
    float* __restrict__ out) {
  __shared__ __align__(16) unsigned short sQ[2][4][64][40];
  __shared__ __align__(16) unsigned short sK[2][4][64][40];
  __shared__ __align__(16) unsigned short sVT[2][4][32][72];
  __shared__ __align__(16) unsigned short sP[4][64][72];

  const int b = blockIdx.x;
  const int tid = (int)threadIdx.x;
  const int wave = tid >> 6;
  const int lane = tid & 63;
  const int quad = lane >> 4;
  const int col = lane & 15;

  // ============================ Phase A: QKV GEMM ===========================
  // wave = (side, nt-group); each wave: full x/y A-frags in regs, 6 nt tiles.
  {
    const int side = wave >> 2;
    const int ntg = wave & 3;
    const float* src = (side ? y : x) + (size_t)b * 8192;
    const unsigned short* wp = side ? wq2p : wq1p;
    const float* bq = side ? bqkv2 : bqkv1;

    short8 afrag[4][4];
#pragma unroll
    for (int mt = 0; mt < 4; ++mt) {
      int m = mt * 16 + col;
#pragma unroll
      for (int ks = 0; ks < 4; ++ks) {
        const float* p = src + m * 128 + ks * 32 + quad * 8;
        float4 lo = *(const float4*)(p);
        float4 hi = *(const float4*)(p + 4);
        short8 f;
        f[0] = (short)f2bf(lo.x); f[1] = (short)f2bf(lo.y);
        f[2] = (short)f2bf(lo.z); f[3] = (short)f2bf(lo.w);
        f[4] = (short)f2bf(hi.x); f[5] = (short)f2bf(hi.y);
        f[6] = (short)f2bf(hi.z); f[7] = (short)f2bf(hi.w);
        afrag[mt][ks] = f;
      }
    }

#pragma unroll 1
    for (int t = 0; t < 6; ++t) {
      int nt = ntg * 6 + t;
      float bias = bq[nt * 16 + col];
      short8 bfrag[4];
#pragma unroll
      for (int ks = 0; ks < 4; ++ks)
        bfrag[ks] = *(const short8*)(wp + (size_t)((nt * 4 + ks) * 64 + lane) * 8);
      int sel = nt >> 3;                 // 0:q 1:k 2:v  (wave-uniform per t)
      int cw = (nt & 7) * 16 + col;      // channel within q/k/v: 0..127
      int h = cw >> 5, d = cw & 31;
#pragma unroll
      for (int mt = 0; mt < 4; ++mt) {
        f32x4 acc = {bias, bias, bias, bias};
#pragma unroll
        for (int ks = 0; ks < 4; ++ks) acc = MFMA(afrag[mt][ks], bfrag[ks], acc);
#pragma unroll
        for (int r = 0; r < 4; ++r) {
          int row = mt * 16 + quad * 4 + r;
          unsigned short v = f2bf(acc[r]);
          if (sel == 0)      sQ[side][h][row][d] = v;
          else if (sel == 1) sK[side][h][row][d] = v;
          else               sVT[side][h][d][row] = v;
        }
      }
    }
  }
  __syncthreads();

  // ============================ Phase B: attention ==========================
  // wave = (head h, row-half rh). Sides sequential (sP reused).
  {
    const float scale = 0.08838834764831845f;  // 1/sqrt(C=128)
    const int h = wave & 3;
    const int rh = wave >> 2;
    const float* mbase = mask + (size_t)(b & 1023) * 4096;

#pragma unroll 1
    for (int s = 0; s < 2; ++s) {
      const float* bt = (s == 0 ? biasT1 : biasT2) + h * 4096;

      float bm[2][4][4];
#pragma unroll
      for (int mi = 0; mi < 2; ++mi) {
        int ib = (2 * rh + mi) * 16 + quad * 4;
#pragma unroll
        for (int nt = 0; nt < 4; ++nt) {
          int jj = nt * 16 + col;
#pragma unroll
          for (int r = 0; r < 4; ++r)
            bm[mi][nt][r] = bt[(ib + r) * 64 + jj] + mbase[(ib + r) * 64 + jj];
        }
      }

      short8 qf[2], kf[4];
#pragma unroll
      for (int mi = 0; mi < 2; ++mi)
        qf[mi] = *(const short8*)&sQ[s][h][(2 * rh + mi) * 16 + col][quad * 8];
#pragma unroll
      for (int nt = 0; nt < 4; ++nt)
        kf[nt] = *(const short8*)&sK[1 - s][h][nt * 16 + col][quad * 8];

      float pv[2][4][4];
#pragma unroll
      for (int mi = 0; mi < 2; ++mi)
#pragma unroll
        for (int nt = 0; nt < 4; ++nt) {
          f32x4 acc = {0.f, 0.f, 0.f, 0.f};
          acc = MFMA(qf[mi], kf[nt], acc);
#pragma unroll
          for (int r = 0; r < 4; ++r)
            pv[mi][nt][r] = fmaf(acc[r], scale, bm[mi][nt][r]);
        }

      // softmax per row; each 16-lane quad owns rows (4 regs x 2 mi)
#pragma unroll
      for (int mi = 0; mi < 2; ++mi)
#pragma unroll
        for (int r = 0; r < 4; ++r) {
          float mx = fmaxf(fmaxf(pv[mi][0][r], pv[mi][1][r]),
                           fmaxf(pv[mi][2][r], pv[mi][3][r]));
          mx = fmaxf(mx, __shfl_xor(mx, 1, 16));
          mx = fmaxf(mx, __shfl_xor(mx, 2, 16));
          mx = fmaxf(mx, __shfl_xor(mx, 4, 16));
          mx = fmaxf(mx, __shfl_xor(mx, 8, 16));
          float sum = 0.f;
#pragma unroll
          for (int nt = 0; nt < 4; ++nt) {
            pv[mi][nt][r] = __expf(pv[mi][nt][r] - mx);
            sum += pv[mi][nt][r];
          }
          sum += __shfl_xor(sum, 1, 16);
          sum += __shfl_xor(sum, 2, 16);
          sum += __shfl_xor(sum, 4, 16);
          sum += __shfl_xor(sum, 8, 16);
          float inv = 1.0f / sum;
          int row = (2 * rh + mi) * 16 + quad * 4 + r;
#pragma unroll
          for (int nt = 0; nt < 4; ++nt)
            sP[h][row][nt * 16 + col] = f2bf(pv[mi][nt][r] * inv);
        }

      __syncthreads();  // also guarantees all S-reads of sQ[s] done before sO alias-write

      short8 pf[2][2], vf[2][2];
#pragma unroll
      for (int mi = 0; mi < 2; ++mi)
#pragma unroll
        for (int ks = 0; ks < 2; ++ks)
          pf[mi][ks] = *(const short8*)&sP[h][(2 * rh + mi) * 16 + col][ks * 32 + quad * 8];
#pragma unroll
      for (int dt = 0; dt < 2; ++dt)
#pragma unroll
        for (int ks = 0; ks < 2; ++ks)
          vf[dt][ks] = *(const short8*)&sVT[1 - s][h][dt * 16 + col][ks * 32 + quad * 8];

      unsigned short* sO = &sQ[s][0][0][0];  // [64][136], q[s] is dead now
#pragma unroll
      for (int mi = 0; mi < 2; ++mi)
#pragma unroll
        for (int dt = 0; dt < 2; ++dt) {
          f32x4 acc = {0.f, 0.f, 0.f, 0.f};
#pragma unroll
          for (int ks = 0; ks < 2; ++ks) acc = MFMA(pf[mi][ks], vf[dt][ks], acc);
#pragma unroll
          for (int r = 0; r < 4; ++r) {
            int row = (2 * rh + mi) * 16 + quad * 4 + r;
            sO[row * 136 + h * 32 + dt * 16 + col] = f2bf(acc[r]);
          }
        }
      __syncthreads();
    }
  }

  // ====================== Phase C: proj + residual + LN =====================
  // wave = (side, row-strip mt): 16 rows x full 128 cols -> in-wave LayerNorm.
  {
    const int side = wave >> 2;
    const int mt = wave & 3;
    const unsigned short* sO = &sQ[side][0][0][0];
    const unsigned short* wpp = side ? wp2p : wp1p;
    const float* bp = side ? bproj2 : bproj1;
    const float* gg = side ? g2 : g1;
    const float* bb = side ? be2 : be1;
    const float* res = (side ? y : x) + (size_t)b * 8192;
    float* o = out + (size_t)side * 33554432 + (size_t)b * 8192;

    short8 af[4];
#pragma unroll
    for (int ks = 0; ks < 4; ++ks)
      af[ks] = *(const short8*)&sO[(mt * 16 + col) * 136 + ks * 32 + quad * 8];

    float vals[8][4];
#pragma unroll
    for (int nt = 0; nt < 8; ++nt) {
      float bias = bp[nt * 16 + col];
      f32x4 acc = {bias, bias, bias, bias};
#pragma unroll
      for (int ks = 0; ks < 4; ++ks)
        acc = MFMA(af[ks], *(const short8*)(wpp + (size_t)((nt * 4 + ks) * 64 + lane) * 8), acc);
#pragma unroll
      for (int r = 0; r < 4; ++r)
        vals[nt][r] = acc[r] + res[(mt * 16 + quad * 4 + r) * 128 + nt * 16 + col];
    }

#pragma unroll
    for (int r = 0; r < 4; ++r) {
      float sum = 0.f;
#pragma unroll
      for (int nt = 0; nt < 8; ++nt) sum += vals[nt][r];
      sum += __shfl_xor(sum, 1, 16);
      sum += __shfl_xor(sum, 2, 16);
      sum += __shfl_xor(sum, 4, 16);
      sum += __shfl_xor(sum, 8, 16);
      float mean = sum * 0.0078125f;
      float vsum = 0.f;
#pragma unroll
      for (int nt = 0; nt < 8; ++nt) {
        float d = vals[nt][r] - mean;
        vsum += d * d;
      }
      vsum += __shfl_xor(vsum, 1, 16);
      vsum += __shfl_xor(vsum, 2, 16);
      vsum += __shfl_xor(vsum, 4, 16);
      vsum += __shfl_xor(vsum, 8, 16);
      float rstd = rsqrtf(vsum * 0.0078125f + 1e-5f);
      int row = mt * 16 + quad * 4 + r;
#pragma unroll
      for (int nt = 0; nt < 8; ++nt) {
        int c = nt * 16 + col;
        o[row * 128 + c] = (vals[nt][r] - mean) * rstd * gg[c] + bb[c];
      }
    }
  }
}

// ---------------------------------------------------------------------------
extern "C" void kernel_launch(void* const* d_in, const int* in_sizes, int n_in,
                              void* d_out, int out_size, void* d_ws, size_t ws_size,
                              hipStream_t stream) {
  const float* x = (const float*)d_in[0];
  const float* y = (const float*)d_in[1];
  const float* mask = (const float*)d_in[2];
  const float* wqkv1 = (const float*)d_in[3];
  const float* bqkv1 = (const float*)d_in[4];
  const float* wqkv2 = (const float*)d_in[5];
  const float* bqkv2 = (const float*)d_in[6];
  const float* tbl1 = (const float*)d_in[7];
  const float* tbl2 = (const float*)d_in[8];
  const float* wproj1 = (const float*)d_in[9];
  const float* bproj1 = (const float*)d_in[10];
  const float* wproj2 = (const float*)d_in[11];
  const float* bproj2 = (const float*)d_in[12];
  const float* g1 = (const float*)d_in[13];
  const float* be1 = (const float*)d_in[14];
  const float* g2 = (const float*)d_in[15];
  const float* be2 = (const float*)d_in[16];
  const int* rpi = (const int*)d_in[17];

  // workspace layout (393216 B total)
  char* ws = (char*)d_ws;
  unsigned short* wq1p = (unsigned short*)(ws + 0);        // 98304
  unsigned short* wq2p = (unsigned short*)(ws + 98304);    // 98304
  unsigned short* wp1p = (unsigned short*)(ws + 196608);   // 32768
  unsigned short* wp2p = (unsigned short*)(ws + 229376);   // 32768
  float* bias1 = (float*)(ws + 262144);                    // 65536
  float* bias2 = (float*)(ws + 327680);                    // 65536

  prep_kernel<<<dim3(192), dim3(256), 0, stream>>>(
      wqkv1, wqkv2, wproj1, wproj2, tbl1, tbl2, rpi,
      wq1p, wq2p, wp1p, wp2p, bias1, bias2);

  wca_kernel<<<dim3(4096), dim3(512), 0, stream>>>(
      x, y, mask, bqkv1, bqkv2, bproj1, bproj2,
      g1, be1, g2, be2, wq1p, wq2p, wp1p, wp2p, bias1, bias2,
      (float*)d_out);
}